// Round 10
// baseline (258.464 us; speedup 1.0000x reference)
//
#include <hip/hip_runtime.h>
#include <hip/hip_bf16.h>

typedef _Float16 half4_t __attribute__((ext_vector_type(4)));
typedef _Float16 half8_t __attribute__((ext_vector_type(8)));
typedef float    float4_t __attribute__((ext_vector_type(4)));

#define MFMA32(a, b, c) __builtin_amdgcn_mfma_f32_16x16x32_f16((a), (b), (c), 0, 0, 0)

constexpr int  Bb  = 1024;
constexpr long CTX = (long)Bb * 64 * 512;      // attn offset in d_out
constexpr int  SQP = 520;                      // sQ (q / V^T) row stride (halves)
constexpr int  QTP = 72;                       // qT row stride (halves), kernel B
constexpr long V2OFF = 524288;                 // V2 offset into ws (halves) = 1 MB bytes

// ---- pre-pass: pack W (f32 [e][f]) into fragment layout fp16 ----
// W2[(E*16+c)*512 + lane*8 + j] = W[E*16+(lane&15)][c*32+(lane>>4)*8+j]
__global__ void w_pack(const float* __restrict__ W, _Float16* __restrict__ W2) {
    const int t = blockIdx.x * 256 + threadIdx.x;      // 32768 threads
    const int lane = t & 63, grp = t >> 6;             // grp 0..511
    const int E = grp >> 4, c = grp & 15;
    const int r16 = lane & 15, q = lane >> 4;
    const float* src = W + (long)(E * 16 + r16) * 512 + c * 32 + q * 8;
    float4_t x = *(const float4_t*)(src);
    float4_t y = *(const float4_t*)(src + 4);
    half8_t h;
    h[0]=(_Float16)x[0]; h[1]=(_Float16)x[1]; h[2]=(_Float16)x[2]; h[3]=(_Float16)x[3];
    h[4]=(_Float16)y[0]; h[5]=(_Float16)y[1]; h[6]=(_Float16)y[2]; h[7]=(_Float16)y[3];
    *(half8_t*)(W2 + (long)t * 8) = h;
}

// ---- kernel V: V^T = q*W^T per batch; write V2 in B-fragment order ----
// V2[b][(gt*16+cc)*512 + lane*8 + j] = V^T[g=gt*16+(lane&15)][e=cc*32+(lane>>4)*8+j]
__global__ __launch_bounds__(512, 3)
void ovo_v(const float* __restrict__ qm, const _Float16* __restrict__ W2,
           _Float16* __restrict__ V2)
{
    __shared__ __align__(16) _Float16 sQ[64 * SQP];   // q fp16, then V^T; 66.6 KB

    const int t = threadIdx.x, lane = t & 63, w = t >> 6;
    const int r16 = lane & 15, q = lane >> 4;
    const long base = (long)blockIdx.x * 64 * 512;
    const float4_t zf4 = {0.f, 0.f, 0.f, 0.f};

    // stage q fp16, flat-linear
    {
        const long qb = base + (long)t * 4;
        #pragma unroll
        for (int k = 0; k < 16; ++k) {
            float4_t v = *(const float4_t*)(qm + qb + (long)k * 2048);
            half4_t h;
            h[0]=(_Float16)v[0]; h[1]=(_Float16)v[1]; h[2]=(_Float16)v[2]; h[3]=(_Float16)v[3];
            *(half4_t*)(&sQ[(k * 4 + (t >> 7)) * SQP + (t & 127) * 4]) = h;
        }
    }
    __syncthreads();

    // V^T[g][e] = sum_f q[g,f]*W[e,f]; wave w owns e-slice [64w, 64w+64)
    float4_t vacc[4][4];   // [g2][et]
    #pragma unroll
    for (int i = 0; i < 4; ++i)
        #pragma unroll
        for (int j = 0; j < 4; ++j) vacc[i][j] = zf4;

    #pragma unroll
    for (int c = 0; c < 16; ++c) {
        half8_t Aq[4], Bw[4];
        #pragma unroll
        for (int g2 = 0; g2 < 4; ++g2)
            Aq[g2] = *(const half8_t*)(&sQ[(g2 * 16 + r16) * SQP + c * 32 + q * 8]);
        #pragma unroll
        for (int et = 0; et < 4; ++et)
            Bw[et] = *(const half8_t*)(W2 + (long)((w * 4 + et) * 16 + c) * 512 + lane * 8);
        #pragma unroll
        for (int g2 = 0; g2 < 4; ++g2)
            #pragma unroll
            for (int et = 0; et < 4; ++et)
                vacc[g2][et] = MFMA32(Aq[g2], Bw[et], vacc[g2][et]);
    }
    __syncthreads();                       // q dead

    // V^T overwrites sQ
    #pragma unroll
    for (int g2 = 0; g2 < 4; ++g2)
        #pragma unroll
        for (int et = 0; et < 4; ++et)
            #pragma unroll
            for (int r = 0; r < 4; ++r)
                sQ[(g2 * 16 + q * 4 + r) * SQP + w * 64 + et * 16 + r16] =
                    (_Float16)vacc[g2][et][r];
    __syncthreads();

    // fragment-order write to V2 (each wave 8 groups; 1 KB linear per wave-instr)
    _Float16* vdst = V2 + (long)blockIdx.x * 32768;
    #pragma unroll
    for (int i = 0; i < 8; ++i) {
        const int grp = w * 8 + i;              // 0..63 = gt*16 + cc
        const int gt = grp >> 4, cc = grp & 15;
        half8_t hv = *(const half8_t*)(&sQ[(gt * 16 + r16) * SQP + cc * 32 + q * 8]);
        *(half8_t*)(vdst + (long)grp * 512 + lane * 8) = hv;
    }
}

// ---- kernel S: score = mean*V streamed; block = (batch, h-quarter); softmax -> attn ----
__global__ __launch_bounds__(256, 4)
void ovo_s(const float* __restrict__ o1, const float* __restrict__ o2,
           const float* __restrict__ o3, const _Float16* __restrict__ V2,
           float* __restrict__ out)
{
    __shared__ float sRed[4][16 * 68];     // 17.4 KB partial-score buffers

    const int t = threadIdx.x, lane = t & 63, w = t >> 6;   // 4 waves = 4 e-slices
    const int r16 = lane & 15, q = lane >> 4;
    const int b  = blockIdx.x >> 2;
    const int hq = blockIdx.x & 3;
    const long base = (long)b * 64 * 512;
    const long abase = base + (long)(hq * 16 + r16) * 512 + w * 128 + q * 8;
    const _Float16* vb = V2 + (long)b * 32768;
    const float4_t zf4 = {0.f, 0.f, 0.f, 0.f};

    float4_t acc0 = zf4, acc1 = zf4, acc2 = zf4, acc3 = zf4;
    float4_t a1A, b1A, a2A, b2A, a3A, b3A;
    float4_t a1B, b1B, a2B, b2B, a3B, b3B;

    #define SLOAD(S, c) do { \
        const long o_ = abase + (c) * 32; \
        a1##S = *(const float4_t*)(o1 + o_); b1##S = *(const float4_t*)(o1 + o_ + 4); \
        a2##S = *(const float4_t*)(o2 + o_); b2##S = *(const float4_t*)(o2 + o_ + 4); \
        a3##S = *(const float4_t*)(o3 + o_); b3##S = *(const float4_t*)(o3 + o_ + 4); \
    } while (0)

    #define SCOMP(S, c) do { \
        float4_t m0 = (a1##S + a2##S + a3##S) * (1.0f / 3.0f); \
        float4_t m1 = (b1##S + b2##S + b3##S) * (1.0f / 3.0f); \
        half8_t af; \
        af[0]=(_Float16)m0[0]; af[1]=(_Float16)m0[1]; af[2]=(_Float16)m0[2]; af[3]=(_Float16)m0[3]; \
        af[4]=(_Float16)m1[0]; af[5]=(_Float16)m1[1]; af[6]=(_Float16)m1[2]; af[7]=(_Float16)m1[3]; \
        half8_t bf0 = *(const half8_t*)(vb + (long)(0 * 16 + w * 4 + (c)) * 512 + lane * 8); \
        half8_t bf1 = *(const half8_t*)(vb + (long)(1 * 16 + w * 4 + (c)) * 512 + lane * 8); \
        half8_t bf2 = *(const half8_t*)(vb + (long)(2 * 16 + w * 4 + (c)) * 512 + lane * 8); \
        half8_t bf3 = *(const half8_t*)(vb + (long)(3 * 16 + w * 4 + (c)) * 512 + lane * 8); \
        acc0 = MFMA32(af, bf0, acc0); \
        acc1 = MFMA32(af, bf1, acc1); \
        acc2 = MFMA32(af, bf2, acc2); \
        acc3 = MFMA32(af, bf3, acc3); \
    } while (0)

    SLOAD(A, 0); SLOAD(B, 1);
    SCOMP(A, 0); SLOAD(A, 2);
    SCOMP(B, 1); SLOAD(B, 3);
    SCOMP(A, 2);
    SCOMP(B, 3);

    // partials: sRed[w][h*68 + g], h=(q*4+r), g=gt*16+r16
    #pragma unroll
    for (int r = 0; r < 4; ++r) {
        sRed[w][(q * 4 + r) * 68 +  0 + r16] = acc0[r];
        sRed[w][(q * 4 + r) * 68 + 16 + r16] = acc1[r];
        sRed[w][(q * 4 + r) * 68 + 32 + r16] = acc2[r];
        sRed[w][(q * 4 + r) * 68 + 48 + r16] = acc3[r];
    }
    __syncthreads();
    if (w == 0) {
        for (int i = 0; i < 17; ++i)
            sRed[0][lane + i * 64] += sRed[2][lane + i * 64];
    }
    if (w == 1) {
        for (int i = 0; i < 17; ++i)
            sRed[1][lane + i * 64] += sRed[3][lane + i * 64];
    }
    __syncthreads();
    if (w == 0) {
        for (int i = 0; i < 17; ++i)
            sRed[0][lane + i * 64] += sRed[1][lane + i * 64];
    }
    __syncthreads();

    // softmax over g (wave 0: 16 rows, 4 lanes/row)
    if (w == 0) {
        const float* srow = &sRed[0][r16 * 68 + q * 16];
        float v[16];
        float mx = -1e30f;
        #pragma unroll
        for (int i = 0; i < 16; ++i) { v[i] = srow[i]; mx = fmaxf(mx, v[i]); }
        mx = fmaxf(mx, __shfl_xor(mx, 16));
        mx = fmaxf(mx, __shfl_xor(mx, 32));
        float sum = 0.f;
        #pragma unroll
        for (int i = 0; i < 16; ++i) { v[i] = __expf(v[i] - mx); sum += v[i]; }
        sum += __shfl_xor(sum, 16);
        sum += __shfl_xor(sum, 32);
        const float inv = 1.0f / sum;
        float* aout = out + CTX + ((long)b * 64 + hq * 16 + r16) * 64 + q * 16;
        #pragma unroll
        for (int i = 0; i < 16; ++i) aout[i] = v[i] * inv;
    }
}

// ---- kernel B: context = attn @ q (unchanged; L3-BW-bound at ~16 us) ----
__global__ __launch_bounds__(256, 4)
void ovo_ctx(const float* __restrict__ qm, const float* __restrict__ out_attn,
             float* __restrict__ out)
{
    __shared__ __align__(16) _Float16 qT[2][64 * QTP];   // q^T chunk [e][g]  36 KB

    const int t = threadIdx.x, lane = t & 63, w = t >> 6;
    const int r16 = lane & 15, q = lane >> 4;
    const long b = blockIdx.x;
    const long base = b * 64 * 512;
    const float4_t zf4 = {0.f, 0.f, 0.f, 0.f};

    const float* ap = out_attn + (b * 64 + w * 16 + r16) * 64 + q * 8;
    half8_t pA0, pA1;
    {
        float4_t x = *(const float4_t*)(ap + 0),  y = *(const float4_t*)(ap + 4);
        pA0[0]=(_Float16)x[0]; pA0[1]=(_Float16)x[1]; pA0[2]=(_Float16)x[2]; pA0[3]=(_Float16)x[3];
        pA0[4]=(_Float16)y[0]; pA0[5]=(_Float16)y[1]; pA0[6]=(_Float16)y[2]; pA0[7]=(_Float16)y[3];
        float4_t z = *(const float4_t*)(ap + 32), u = *(const float4_t*)(ap + 36);
        pA1[0]=(_Float16)z[0]; pA1[1]=(_Float16)z[1]; pA1[2]=(_Float16)z[2]; pA1[3]=(_Float16)z[3];
        pA1[4]=(_Float16)u[0]; pA1[5]=(_Float16)u[1]; pA1[6]=(_Float16)u[2]; pA1[7]=(_Float16)u[3];
    }

    const int sg = t & 63, se = (t >> 6) * 16;
    const float* qsrc = qm + base + (long)sg * 512 + se;
    float4_t rA[4], rB[4];

    #define QLOAD(R, c) do { \
        _Pragma("unroll") \
        for (int i = 0; i < 4; ++i) R[i] = *(const float4_t*)(qsrc + (c) * 64 + i * 4); \
    } while (0)
    #define QCOMMIT(R, buf) do { \
        _Pragma("unroll") \
        for (int i = 0; i < 4; ++i) \
            _Pragma("unroll") \
            for (int jj = 0; jj < 4; ++jj) \
                qT[buf][(se + i * 4 + jj) * QTP + sg] = (_Float16)R[i][jj]; \
    } while (0)
    #define BCOMP(c, buf) do { \
        _Pragma("unroll") \
        for (int et = 0; et < 4; ++et) { \
            half8_t b0 = *(const half8_t*)(&qT[buf][(et * 16 + r16) * QTP + q * 8]); \
            half8_t b1 = *(const half8_t*)(&qT[buf][(et * 16 + r16) * QTP + 32 + q * 8]); \
            float4_t acc = MFMA32(pA0, b0, zf4); \
            acc = MFMA32(pA1, b1, acc); \
            _Pragma("unroll") \
            for (int rr = 0; rr < 4; ++rr) \
                out[(b * 64 + w * 16 + q * 4 + rr) * 512 + (c) * 64 + et * 16 + r16] = acc[rr]; \
        } \
    } while (0)

    QLOAD(rA, 0);
    QCOMMIT(rA, 0);
    __syncthreads();
    #pragma unroll
    for (int cc = 0; cc < 8; cc += 2) {
        QLOAD(rB, cc + 1);
        BCOMP(cc, 0);
        QCOMMIT(rB, 1);
        __syncthreads();
        if (cc + 2 < 8) QLOAD(rA, cc + 2);
        BCOMP(cc + 1, 1);
        if (cc + 2 < 8) QCOMMIT(rA, 0);
        __syncthreads();
    }
}

extern "C" void kernel_launch(void* const* d_in, const int* in_sizes, int n_in,
                              void* d_out, int out_size, void* d_ws, size_t ws_size,
                              hipStream_t stream) {
    const float* o1 = (const float*)d_in[0];
    const float* o2 = (const float*)d_in[1];
    const float* o3 = (const float*)d_in[2];
    const float* qm = (const float*)d_in[3];
    const float* W  = (const float*)d_in[4];
    float* out = (float*)d_out;
    _Float16* W2 = (_Float16*)d_ws;                 // 512 KB fragment-layout fp16 W
    _Float16* V2 = (_Float16*)d_ws + V2OFF;         // 67 MB fragment-layout fp16 V

    w_pack<<<dim3(128), dim3(256), 0, stream>>>(W, W2);
    ovo_v<<<dim3(Bb), dim3(512), 0, stream>>>(qm, W2, V2);
    ovo_s<<<dim3(Bb * 4), dim3(256), 0, stream>>>(o1, o2, o3, V2, out);
    ovo_ctx<<<dim3(Bb), dim3(256), 0, stream>>>(qm, out + CTX, out);
}